// Round 2
// baseline (683.617 us; speedup 1.0000x reference)
//
#include <hip/hip_runtime.h>

#define N_NODES 20000
#define N_EDGES 320000
#define DIM 256
#define H_HEADS 4

typedef _Float16 f16x8 __attribute__((ext_vector_type(8)));
typedef float f32x4v __attribute__((ext_vector_type(4)));

// ---------------- init: convert W to f16 transposed, zero counts ----------------
__global__ void k_init(const float* __restrict__ Wn, const float* __restrict__ We,
                       _Float16* __restrict__ WTn, _Float16* __restrict__ WTe,
                       unsigned int* __restrict__ counts)
{
    int i = blockIdx.x * 256 + threadIdx.x;
    if (i < DIM * DIM) {
        int n = i >> 8, k = i & 255;
        WTn[i] = (_Float16)Wn[k * DIM + n];
        WTe[i] = (_Float16)We[k * DIM + n];
    }
    if (i <= N_NODES) counts[i] = 0u;
}

// ---------------- CSR build ----------------
__global__ void k_hist(const int* __restrict__ dst, unsigned int* __restrict__ counts)
{
    int i = blockIdx.x * 256 + threadIdx.x;
    if (i < N_EDGES) atomicAdd(&counts[dst[i]], 1u);
}

// single-pass chunked scan: 1024 threads x 20 elements, one shuffle-scan, 2 barriers
__global__ __launch_bounds__(1024) void k_scan(unsigned int* __restrict__ counts,
                                               unsigned int* __restrict__ cursor)
{
    __shared__ unsigned int wsum[16];
    const int t = threadIdx.x, lane = t & 63, wv = t >> 6;
    const int CH = 20;                       // 1024*20 = 20480 >= 20001
    unsigned int v[CH];
    const int base = t * CH;
    unsigned int sum = 0;
#pragma unroll
    for (int i = 0; i < CH; ++i) {
        int idx = base + i;
        v[i] = (idx < N_NODES) ? counts[idx] : 0u;
        sum += v[i];
    }
    unsigned int x = sum;
#pragma unroll
    for (int off = 1; off < 64; off <<= 1) {
        unsigned int y = __shfl_up(x, off);
        if (lane >= off) x += y;
    }
    if (lane == 63) wsum[wv] = x;
    __syncthreads();
    if (t < 16) {
        unsigned int s = wsum[t];
#pragma unroll
        for (int off = 1; off < 16; off <<= 1) {
            unsigned int y = __shfl_up(s, off);
            if (t >= off) s += y;
        }
        wsum[t] = s;                          // inclusive scan of wave sums
    }
    __syncthreads();
    unsigned int run = (wv ? wsum[wv - 1] : 0u) + x - sum;   // exclusive base
#pragma unroll
    for (int i = 0; i < CH; ++i) {
        int idx = base + i;
        if (idx < N_NODES) { counts[idx] = run; cursor[idx] = run; }
        run += v[i];
    }
    if (t == 1023) counts[N_NODES] = run;     // = N_EDGES
}

__global__ void k_scatter(const int* __restrict__ dst, unsigned int* __restrict__ cursor,
                          int* __restrict__ esort)
{
    int i = blockIdx.x * 256 + threadIdx.x;
    if (i < N_EDGES) {
        unsigned int p = atomicAdd(&cursor[dst[i]], 1u);
        esort[p] = i;
    }
}

// ---------------- node projection GEMM: ft = nfeat @ W_node (f32 out) ----------------
__global__ __launch_bounds__(256) void k_gemm_node(
    const float* __restrict__ A, const _Float16* __restrict__ WT,
    float* __restrict__ C, int M)
{
    __shared__ __align__(16) _Float16 Alds[64][40];
    const int t = threadIdx.x;
    const int m0 = blockIdx.x * 64;
    const int lane = t & 63, w = t >> 6;
    const int q = lane >> 4, c16 = lane & 15;
    const int srow = t >> 2;
    const int skb = (t & 3) * 8;
    f32x4v acc[4][4] = {};

    const int grow = m0 + srow;
    const bool valid = grow < M;
    const float* gp = A + (size_t)grow * DIM + skb;
    f32x4v p0[2] = {}, p1[2] = {};            // depth-2 prefetch buffers
    if (valid) {
        p0[0] = __builtin_nontemporal_load((const f32x4v*)gp);
        p1[0] = __builtin_nontemporal_load((const f32x4v*)(gp + 4));
        p0[1] = __builtin_nontemporal_load((const f32x4v*)(gp + 32));
        p1[1] = __builtin_nontemporal_load((const f32x4v*)(gp + 36));
    }

#pragma unroll
    for (int s = 0; s < 8; ++s) {
        const int k0 = s * 32;
        const int b = s & 1;
        f16x8 h8;
        h8[0]=(_Float16)p0[b][0]; h8[1]=(_Float16)p0[b][1]; h8[2]=(_Float16)p0[b][2]; h8[3]=(_Float16)p0[b][3];
        h8[4]=(_Float16)p1[b][0]; h8[5]=(_Float16)p1[b][1]; h8[6]=(_Float16)p1[b][2]; h8[7]=(_Float16)p1[b][3];
        __syncthreads();
        *(f16x8*)&Alds[srow][skb] = h8;
        __syncthreads();
        if (s < 6 && valid) {                 // issue load for step s+2
            p0[b] = __builtin_nontemporal_load((const f32x4v*)(gp + k0 + 64));
            p1[b] = __builtin_nontemporal_load((const f32x4v*)(gp + k0 + 68));
        }

        f16x8 bfr[4], afr[4];
#pragma unroll
        for (int ni = 0; ni < 4; ++ni) {
            int col = (w << 6) + (ni << 4) + c16;
            bfr[ni] = *(const f16x8*)(WT + (size_t)col * DIM + k0 + q * 8);
        }
#pragma unroll
        for (int mi = 0; mi < 4; ++mi)
            afr[mi] = *(const f16x8*)&Alds[c16 + 16 * mi][q * 8];
#pragma unroll
        for (int mi = 0; mi < 4; ++mi)
#pragma unroll
            for (int ni = 0; ni < 4; ++ni)
                acc[mi][ni] = __builtin_amdgcn_mfma_f32_16x16x32_f16(afr[mi], bfr[ni], acc[mi][ni], 0, 0, 0);
    }

#pragma unroll
    for (int mi = 0; mi < 4; ++mi) {
#pragma unroll
        for (int reg = 0; reg < 4; ++reg) {
            int row = m0 + 16 * mi + 4 * q + reg;
            if (row < M) {
#pragma unroll
                for (int ni = 0; ni < 4; ++ni) {
                    int c = (w << 6) + (ni << 4) + c16;
                    C[(size_t)row * DIM + c] = acc[mi][ni][reg];
                }
            }
        }
    }
}

// ---------------- fused edge GEMM in dst-sorted order: ftp (sorted), a (sorted) ----------------
__global__ __launch_bounds__(256) void k_gemm_edge(
    const float* __restrict__ efeat, const _Float16* __restrict__ WT,
    const float* __restrict__ ft, const int* __restrict__ src, const int* __restrict__ dst,
    const int* __restrict__ esort,
    _Float16* __restrict__ ftp, float* __restrict__ a_ws)
{
    __shared__ __align__(16) _Float16 Alds[64][40];
    __shared__ int eidx[64], ssrc[64], sdst[64];
    const int t = threadIdx.x;
    const int e0 = blockIdx.x * 64;
    const int lane = t & 63, w = t >> 6;
    const int q = lane >> 4, c16 = lane & 15;
    const int srow = t >> 2;
    const int skb = (t & 3) * 8;
    f32x4v acc[4][4] = {};

    if (t < 64) {
        int e = esort[e0 + t];
        eidx[t] = e;
        ssrc[t] = src[e];
        sdst[t] = dst[e];
    }
    __syncthreads();

    const float* gp = efeat + (size_t)eidx[srow] * DIM + skb;
    f32x4v p0[2], p1[2];                      // depth-2 prefetch buffers
    p0[0] = __builtin_nontemporal_load((const f32x4v*)gp);
    p1[0] = __builtin_nontemporal_load((const f32x4v*)(gp + 4));
    p0[1] = __builtin_nontemporal_load((const f32x4v*)(gp + 32));
    p1[1] = __builtin_nontemporal_load((const f32x4v*)(gp + 36));

#pragma unroll
    for (int s = 0; s < 8; ++s) {
        const int k0 = s * 32;
        const int b = s & 1;
        f16x8 h8;
        h8[0]=(_Float16)p0[b][0]; h8[1]=(_Float16)p0[b][1]; h8[2]=(_Float16)p0[b][2]; h8[3]=(_Float16)p0[b][3];
        h8[4]=(_Float16)p1[b][0]; h8[5]=(_Float16)p1[b][1]; h8[6]=(_Float16)p1[b][2]; h8[7]=(_Float16)p1[b][3];
        __syncthreads();
        *(f16x8*)&Alds[srow][skb] = h8;
        __syncthreads();
        if (s < 6) {                          // issue load for step s+2
            p0[b] = __builtin_nontemporal_load((const f32x4v*)(gp + k0 + 64));
            p1[b] = __builtin_nontemporal_load((const f32x4v*)(gp + k0 + 68));
        }

        f16x8 bfr[4], afr[4];
#pragma unroll
        for (int ni = 0; ni < 4; ++ni) {
            int col = (w << 6) + (ni << 4) + c16;
            bfr[ni] = *(const f16x8*)(WT + (size_t)col * DIM + k0 + q * 8);
        }
#pragma unroll
        for (int mi = 0; mi < 4; ++mi)
            afr[mi] = *(const f16x8*)&Alds[c16 + 16 * mi][q * 8];
#pragma unroll
        for (int mi = 0; mi < 4; ++mi)
#pragma unroll
            for (int ni = 0; ni < 4; ++ni)
                acc[mi][ni] = __builtin_amdgcn_mfma_f32_16x16x32_f16(afr[mi], bfr[ni], acc[mi][ni], 0, 0, 0);
    }

    // epilogue: ft_prime = eft + ft[src] (stored at SORTED position); a = dot(ft_prime, ft[dst])
#pragma unroll
    for (int mi = 0; mi < 4; ++mi) {
#pragma unroll
        for (int reg = 0; reg < 4; ++reg) {
            const int r = 16 * mi + 4 * q + reg;
            const int s = e0 + r;                       // sorted position
            const float* fsrc = ft + (size_t)ssrc[r] * DIM;
            const float* fdst = ft + (size_t)sdst[r] * DIM;
            float dotp = 0.f;
#pragma unroll
            for (int ni = 0; ni < 4; ++ni) {
                int c = (w << 6) + (ni << 4) + c16;
                float v = acc[mi][ni][reg] + fsrc[c];
                ftp[(size_t)s * DIM + c] = (_Float16)v;
                dotp += v * fdst[c];
            }
            dotp += __shfl_xor(dotp, 1);
            dotp += __shfl_xor(dotp, 2);
            dotp += __shfl_xor(dotp, 4);
            dotp += __shfl_xor(dotp, 8);
            if (c16 == 0) a_ws[s * H_HEADS + w] = dotp;
        }
    }
}

// ---------------- fused softmax + aggregation: one wave per node, 4 edges/iter ----------------
__global__ __launch_bounds__(256) void k_agg(
    const unsigned int* __restrict__ offs, const float* __restrict__ a_ws,
    const _Float16* __restrict__ ftp, float* __restrict__ out)
{
    const int n = blockIdx.x * 4 + (threadIdx.x >> 6);
    const int lane = threadIdx.x & 63;
    const int beg = (int)offs[n], end = (int)offs[n + 1];

    // pass A: per-head max (lane's elements all have head lane&3)
    float m = -1e30f;
    for (int j = beg * 4 + lane; j < end * 4; j += 64)
        m = fmaxf(m, a_ws[j]);
    m = fmaxf(m, __shfl_xor(m, 4));
    m = fmaxf(m, __shfl_xor(m, 8));
    m = fmaxf(m, __shfl_xor(m, 16));
    m = fmaxf(m, __shfl_xor(m, 32));

    // pass B: per-head sum of exp
    float sm = 0.f;
    for (int j = beg * 4 + lane; j < end * 4; j += 64)
        sm += __expf(a_ws[j] - m);
    sm += __shfl_xor(sm, 4);
    sm += __shfl_xor(sm, 8);
    sm += __shfl_xor(sm, 16);
    sm += __shfl_xor(sm, 32);

    // pass C: 4 edges per iteration, 16 lanes per edge, 32 B per lane
    const int quarter = lane >> 4;       // which of 4 edges
    const int cl = lane & 15;
    const int cb = cl * 16;              // col base (16 f16 per lane)
    const int hc = cl >> 2;              // head of these cols
    const float mh = __shfl(m, hc);
    const float sh = __shfl(sm, hc);
    const float inv = (end > beg) ? 0.125f / sh : 0.f;

    float acc[16] = {};
    for (int j = beg + quarter; j < end; j += 4) {
        float wj = __expf(a_ws[j * H_HEADS + hc] - mh);
        const _Float16* fp = ftp + (size_t)j * DIM + cb;
        f16x8 d0 = *(const f16x8*)fp;
        f16x8 d1 = *(const f16x8*)(fp + 8);
#pragma unroll
        for (int k = 0; k < 8; ++k) {
            acc[k]     += wj * (float)d0[k];
            acc[k + 8] += wj * (float)d1[k];
        }
    }
#pragma unroll
    for (int k = 0; k < 16; ++k) {
        acc[k] += __shfl_xor(acc[k], 16);
        acc[k] += __shfl_xor(acc[k], 32);
    }

    if (quarter == 0) {
        float* op = out + (size_t)n * DIM + cb;
#pragma unroll
        for (int v4 = 0; v4 < 4; ++v4) {
            float4 o = make_float4(acc[v4*4+0] * inv, acc[v4*4+1] * inv,
                                   acc[v4*4+2] * inv, acc[v4*4+3] * inv);
            *(float4*)(op + v4 * 4) = o;
        }
    }
}

// ---------------- launch ----------------
extern "C" void kernel_launch(void* const* d_in, const int* in_sizes, int n_in,
                              void* d_out, int out_size, void* d_ws, size_t ws_size,
                              hipStream_t stream)
{
    const float* nfeat = (const float*)d_in[0];
    const float* efeat = (const float*)d_in[1];
    const int* src = (const int*)d_in[2];
    const int* dst = (const int*)d_in[3];
    const float* Wn = (const float*)d_in[4];
    const float* We = (const float*)d_in[5];
    float* out = (float*)d_out;

    char* ws = (char*)d_ws;
    size_t off = 0;
    auto alloc = [&](size_t bytes) -> void* {
        off = (off + 255) & ~(size_t)255;
        void* p = ws + off;
        off += bytes;
        return p;
    };

    _Float16* WTn = (_Float16*)alloc((size_t)DIM * DIM * 2);
    _Float16* WTe = (_Float16*)alloc((size_t)DIM * DIM * 2);
    float* ft = (float*)alloc((size_t)N_NODES * DIM * 4);
    _Float16* ftp = (_Float16*)alloc((size_t)N_EDGES * DIM * 2);
    float* a_ws = (float*)alloc((size_t)N_EDGES * H_HEADS * 4);
    unsigned int* counts = (unsigned int*)alloc((size_t)(N_NODES + 1) * 4);
    unsigned int* cursor = (unsigned int*)alloc((size_t)N_NODES * 4);
    int* esort = (int*)alloc((size_t)N_EDGES * 4);

    k_init<<<256, 256, 0, stream>>>(Wn, We, WTn, WTe, counts);
    k_hist<<<(N_EDGES + 255) / 256, 256, 0, stream>>>(dst, counts);
    k_scan<<<1, 1024, 0, stream>>>(counts, cursor);
    k_scatter<<<(N_EDGES + 255) / 256, 256, 0, stream>>>(dst, cursor, esort);
    k_gemm_node<<<(N_NODES + 63) / 64, 256, 0, stream>>>(nfeat, WTn, ft, N_NODES);
    k_gemm_edge<<<N_EDGES / 64, 256, 0, stream>>>(efeat, WTe, ft, src, dst, esort, ftp, a_ws);
    k_agg<<<N_NODES / 4, 256, 0, stream>>>(counts, a_ws, ftp, out);
}